// Round 2
// baseline (1054.763 us; speedup 1.0000x reference)
//
#include <hip/hip_runtime.h>
#include <math.h>

#define TOKENS 16384   // B*S = 4*4096
#define DDIM   4096
#define NEXP   128
#define TOPK   8

// ================= split-K GEMM (phase 1) =================
#define KSPLIT 4
#define KCH    (DDIM / KSPLIT)   // 1024 K per block
#define BK     32
#define NC     (KCH / BK)        // 32 chunks
#define TM     64                // tokens per block
#define STRIDE 36                // padded row stride (floats); 144B -> <=2-way conflicts

__global__ __launch_bounds__(256, 4)
void gemm_partial(const float* __restrict__ x,
                  const float* __restrict__ W,
                  double* __restrict__ part)
{
    __shared__ __align__(16) float smem[(TM + NEXP) * STRIDE];  // 27648 B
    float* xs = smem;                 // [64][36]
    float* ws = smem + TM * STRIDE;   // [128][36]

    const int t      = threadIdx.x;
    const int tokblk = blockIdx.x & 255;
    const int ks     = blockIdx.x >> 8;
    const int tok0   = tokblk * TM;
    const int kbase  = ks * KCH;

    const int el = t & 15;    // expert lane: experts el + 16*j
    const int tg = t >> 4;    // token group: tokens tg*4 + i

    double acc[4][8];
    #pragma unroll
    for (int i = 0; i < 4; ++i)
        #pragma unroll
        for (int j = 0; j < 8; ++j) acc[i][j] = 0.0;

    float4 gx[2], gw[4];

    // prefetch chunk 0:
    // x: 512 float4 (64 rows x 8), q = t + 256r ; W: 1024 float4 (128 rows x 8)
    {
        const int k0 = kbase;
        #pragma unroll
        for (int r = 0; r < 2; ++r) {
            const int q = t + r * 256;
            gx[r] = *reinterpret_cast<const float4*>(
                &x[(size_t)(tok0 + (q >> 3)) * DDIM + k0 + (q & 7) * 4]);
        }
        #pragma unroll
        for (int r = 0; r < 4; ++r) {
            const int q = t + r * 256;
            gw[r] = *reinterpret_cast<const float4*>(
                &W[(size_t)(q >> 3) * DDIM + k0 + (q & 7) * 4]);
        }
    }

    #pragma unroll 1
    for (int c = 0; c < NC; ++c) {
        __syncthreads();
        #pragma unroll
        for (int r = 0; r < 2; ++r) {
            const int q = t + r * 256;
            *reinterpret_cast<float4*>(&xs[(q >> 3) * STRIDE + (q & 7) * 4]) = gx[r];
        }
        #pragma unroll
        for (int r = 0; r < 4; ++r) {
            const int q = t + r * 256;
            *reinterpret_cast<float4*>(&ws[(q >> 3) * STRIDE + (q & 7) * 4]) = gw[r];
        }
        __syncthreads();

        // issue next chunk's global loads (hidden under FMA block)
        if (c + 1 < NC) {
            const int k0 = kbase + (c + 1) * BK;
            #pragma unroll
            for (int r = 0; r < 2; ++r) {
                const int q = t + r * 256;
                gx[r] = *reinterpret_cast<const float4*>(
                    &x[(size_t)(tok0 + (q >> 3)) * DDIM + k0 + (q & 7) * 4]);
            }
            #pragma unroll
            for (int r = 0; r < 4; ++r) {
                const int q = t + r * 256;
                gw[r] = *reinterpret_cast<const float4*>(
                    &W[(size_t)(q >> 3) * DDIM + k0 + (q & 7) * 4]);
            }
        }

        // fp64 accumulate: 8 kk-steps x 128 fma
        #pragma unroll 2
        for (int kk = 0; kk < BK; kk += 4) {
            float4 xa[4], wb[8];
            #pragma unroll
            for (int i = 0; i < 4; ++i)
                xa[i] = *reinterpret_cast<const float4*>(&xs[(tg * 4 + i) * STRIDE + kk]);
            #pragma unroll
            for (int j = 0; j < 8; ++j)
                wb[j] = *reinterpret_cast<const float4*>(&ws[(el + 16 * j) * STRIDE + kk]);
            #pragma unroll
            for (int i = 0; i < 4; ++i) {
                #pragma unroll
                for (int j = 0; j < 8; ++j) {
                    acc[i][j] = fma((double)xa[i].x, (double)wb[j].x, acc[i][j]);
                    acc[i][j] = fma((double)xa[i].y, (double)wb[j].y, acc[i][j]);
                    acc[i][j] = fma((double)xa[i].z, (double)wb[j].z, acc[i][j]);
                    acc[i][j] = fma((double)xa[i].w, (double)wb[j].w, acc[i][j]);
                }
            }
        }
    }

    // write fp64 partials to workspace: part[ks][tok][exp]
    const size_t base = ((size_t)ks * TOKENS + tok0) * (size_t)NEXP;
    #pragma unroll
    for (int i = 0; i < 4; ++i)
        #pragma unroll
        for (int j = 0; j < 8; ++j)
            part[base + (size_t)(tg * 4 + i) * NEXP + el + 16 * j] = acc[i][j];
}

// ================= reduce + softmax + top-8 (phase 2) =================
__global__ __launch_bounds__(256)
void reduce_topk(const double* __restrict__ part,
                 const float* __restrict__ b,
                 float* __restrict__ out)
{
    const int lane = threadIdx.x & 63;
    const int wv   = threadIdx.x >> 6;
    const size_t T = (size_t)blockIdx.x * 4 + wv;   // one token per wave
    const int e1 = lane, e2 = lane + 64;

    // fixed-order fp64 reduction of K-split partials
    double v1 = 0.0, v2 = 0.0;
    #pragma unroll
    for (int ks = 0; ks < KSPLIT; ++ks) {
        const double* p = &part[((size_t)ks * TOKENS + T) * NEXP];
        v1 += p[e1];
        v2 += p[e2];
    }
    v1 += (double)b[e1];
    v2 += (double)b[e2];

    // wave max (fp64, exact ordering basis)
    double mx = fmax(v1, v2);
    #pragma unroll
    for (int off = 32; off > 0; off >>= 1)
        mx = fmax(mx, __shfl_xor(mx, off, 64));

    // softmax denominator in fp32 (score tolerance is loose; ordering uses fp64)
    float s = expf((float)(v1 - mx)) + expf((float)(v2 - mx));
    #pragma unroll
    for (int off = 32; off > 0; off >>= 1)
        s += __shfl_xor(s, off, 64);

    // 8 argmax rounds on fp64 logits; tie -> lower index (jax.lax.top_k)
    double w1 = v1, w2 = v2;
    for (int r = 0; r < TOPK; ++r) {
        double bv = w1; int bi = e1;
        if (w2 > bv) { bv = w2; bi = e2; }     // e2>e1: tie keeps e1
        #pragma unroll
        for (int off = 32; off > 0; off >>= 1) {
            double ov = __shfl_xor(bv, off, 64);
            int    oi = __shfl_xor(bi, off, 64);
            if (ov > bv || (ov == bv && oi < bi)) { bv = ov; bi = oi; }
        }
        if (lane == 0) {
            out[T * TOPK + r] = expf((float)(bv - mx)) / s;
            out[(size_t)TOKENS * TOPK + T * TOPK + r] = (float)bi;
        }
        if (bi == e1) w1 = -1e300;
        if (bi == e2) w2 = -1e300;
    }
}

// ================= fallback: verified round-1 monolithic kernel =================
#define MBK   64
#define MBKP  68

__global__ __launch_bounds__(256, 1)
void router_mono(const float* __restrict__ x,
                 const float* __restrict__ W,
                 const float* __restrict__ b,
                 float* __restrict__ out)
{
    __shared__ __align__(16) char smem[TM * NEXP * 8];
    float*  xs = (float*)smem;
    float*  ws = (float*)smem + TM * MBKP;
    double* lg = (double*)smem;

    const int t    = threadIdx.x;
    const int wg   = blockIdx.x;
    const int tok0 = wg * TM;

    const int el  = t & 15;
    const int tg  = t >> 4;
    const int sub = t >> 4;
    const int q4  = (t & 15) * 4;

    double acc[4][8];
    #pragma unroll
    for (int i = 0; i < 4; ++i)
        #pragma unroll
        for (int j = 0; j < 8; ++j) acc[i][j] = 0.0;

    float4 gx[4], gw[8];
    {
        #pragma unroll
        for (int i = 0; i < 4; ++i)
            gx[i] = *reinterpret_cast<const float4*>(
                &x[(size_t)(tok0 + i * 16 + sub) * DDIM + q4]);
        #pragma unroll
        for (int j = 0; j < 8; ++j)
            gw[j] = *reinterpret_cast<const float4*>(
                &W[(size_t)(j * 16 + sub) * DDIM + q4]);
    }

    #pragma unroll 1
    for (int c = 0; c < DDIM / MBK; ++c) {
        __syncthreads();
        #pragma unroll
        for (int i = 0; i < 4; ++i)
            *reinterpret_cast<float4*>(&xs[(i * 16 + sub) * MBKP + q4]) = gx[i];
        #pragma unroll
        for (int j = 0; j < 8; ++j)
            *reinterpret_cast<float4*>(&ws[(j * 16 + sub) * MBKP + q4]) = gw[j];
        __syncthreads();

        if (c + 1 < DDIM / MBK) {
            const int k0 = (c + 1) * MBK;
            #pragma unroll
            for (int i = 0; i < 4; ++i)
                gx[i] = *reinterpret_cast<const float4*>(
                    &x[(size_t)(tok0 + i * 16 + sub) * DDIM + k0 + q4]);
            #pragma unroll
            for (int j = 0; j < 8; ++j)
                gw[j] = *reinterpret_cast<const float4*>(
                    &W[(size_t)(j * 16 + sub) * DDIM + k0 + q4]);
        }

        #pragma unroll 2
        for (int kk = 0; kk < MBK; kk += 4) {
            float4 xa[4], wb[8];
            #pragma unroll
            for (int i = 0; i < 4; ++i)
                xa[i] = *reinterpret_cast<const float4*>(&xs[(tg * 4 + i) * MBKP + kk]);
            #pragma unroll
            for (int j = 0; j < 8; ++j)
                wb[j] = *reinterpret_cast<const float4*>(&ws[(el + 16 * j) * MBKP + kk]);
            #pragma unroll
            for (int i = 0; i < 4; ++i) {
                #pragma unroll
                for (int j = 0; j < 8; ++j) {
                    acc[i][j] = fma((double)xa[i].x, (double)wb[j].x, acc[i][j]);
                    acc[i][j] = fma((double)xa[i].y, (double)wb[j].y, acc[i][j]);
                    acc[i][j] = fma((double)xa[i].z, (double)wb[j].z, acc[i][j]);
                    acc[i][j] = fma((double)xa[i].w, (double)wb[j].w, acc[i][j]);
                }
            }
        }
    }

    __syncthreads();
    #pragma unroll
    for (int i = 0; i < 4; ++i)
        #pragma unroll
        for (int j = 0; j < 8; ++j)
            lg[(tg * 4 + i) * NEXP + (el + 16 * j)] = acc[i][j];
    __syncthreads();

    const int lane = t & 63;
    const int wv   = t >> 6;

    for (int it = 0; it < TM / 4; ++it) {
        const int m = wv * 16 + it;
        const int e1 = lane, e2 = lane + 64;
        double v1 = lg[m * NEXP + e1] + (double)b[e1];
        double v2 = lg[m * NEXP + e2] + (double)b[e2];

        double mx = fmax(v1, v2);
        #pragma unroll
        for (int off = 32; off > 0; off >>= 1)
            mx = fmax(mx, __shfl_xor(mx, off, 64));

        double s = exp(v1 - mx) + exp(v2 - mx);
        #pragma unroll
        for (int off = 32; off > 0; off >>= 1)
            s += __shfl_xor(s, off, 64);

        double w1 = v1, w2 = v2;
        for (int r = 0; r < TOPK; ++r) {
            double bv = w1; int bi = e1;
            if (w2 > bv) { bv = w2; bi = e2; }
            #pragma unroll
            for (int off = 32; off > 0; off >>= 1) {
                double ov = __shfl_xor(bv, off, 64);
                int    oi = __shfl_xor(bi, off, 64);
                if (ov > bv || (ov == bv && oi < bi)) { bv = ov; bi = oi; }
            }
            if (lane == 0) {
                const size_t T = (size_t)tok0 + m;
                out[T * TOPK + r] = (float)(exp(bv - mx) / s);
                out[(size_t)TOKENS * TOPK + T * TOPK + r] = (float)bi;
            }
            if (bi == e1) w1 = -1e300;
            if (bi == e2) w2 = -1e300;
        }
    }
}

extern "C" void kernel_launch(void* const* d_in, const int* in_sizes, int n_in,
                              void* d_out, int out_size, void* d_ws, size_t ws_size,
                              hipStream_t stream) {
    const float* x = (const float*)d_in[0];
    const float* W = (const float*)d_in[1];
    const float* b = (const float*)d_in[2];
    float* out = (float*)d_out;

    const size_t need = (size_t)KSPLIT * TOKENS * NEXP * sizeof(double);  // 64 MB
    if (ws_size >= need) {
        double* part = (double*)d_ws;
        hipLaunchKernelGGL(gemm_partial, dim3(256 * KSPLIT), dim3(256), 0, stream,
                           x, W, part);
        hipLaunchKernelGGL(reduce_topk, dim3(TOKENS / 4), dim3(256), 0, stream,
                           part, b, out);
    } else {
        hipLaunchKernelGGL(router_mono, dim3(TOKENS / TM), dim3(256), 0, stream,
                           x, W, b, out);
    }
}